// Round 1
// 183.007 us; speedup vs baseline: 1.0201x; 1.0201x over previous
//
#include <hip/hip_runtime.h>
#include <math.h>

// iSQRT-COV: B=64, C=128, n=3136.
// 1) gram: packed SYMMETRIC Gpart (36 of 64 16x16 tiles) via split-bf16 MFMA,
//    448 blocks; all 4 waves share the 8 row-fragments, 9 tiles/wave.
// 2) ns: fused reduce + Newton-Schulz. Prologue: sum K-partials (fp32),
//    sigma = G/n - mu mu^T, in-block trace reduce, write swizzled planes
//    (mirrored from packed upper-tri). Then NS as before: 64 blocks x 1024
//    threads, XOR-swizzled LDS planes, P2||P3 wave split.

#define CC 128
#define NN 3136
#define BB 64
#define KS 7
#define KCHUNK 448            // NN/KS = 7 iterations of 64 cols
#define MATS (CC * CC)
#define OUTLEN 8256
#define SSTR 66               // gram stage row stride in bf16 (33 dwords, odd)
#define NTILE 36              // packed upper-tri 16x16 tiles of the 8x8 grid

// ns plane addressing: row n, short-index ks in [0,128); 16B-granule XOR swizzle
#define NSW(n, ks) (((n) << 7) + (((((ks) >> 3) ^ ((n) & 15)) << 3) | ((ks) & 7)))

typedef float f32x4 __attribute__((ext_vector_type(4)));
typedef short s16x8 __attribute__((ext_vector_type(8)));
typedef short s16x4 __attribute__((ext_vector_type(4)));
typedef __bf16 bf16x8 __attribute__((ext_vector_type(8)));

// slot -> (tile_i, tile_j), upper-tri row-major enumeration (i<=j)
__constant__ int SLI[NTILE] = {0,0,0,0,0,0,0,0, 1,1,1,1,1,1,1, 2,2,2,2,2,2,
                               3,3,3,3,3, 4,4,4,4, 5,5,5, 6,6, 7};
__constant__ int SLJ[NTILE] = {0,1,2,3,4,5,6,7, 1,2,3,4,5,6,7, 2,3,4,5,6,7,
                               3,4,5,6,7, 4,5,6,7, 5,6,7, 6,7, 7};

__device__ __forceinline__ unsigned short f2b(float f) {
    unsigned u = __builtin_bit_cast(unsigned, f);
    unsigned r = u + 0x7fffu + ((u >> 16) & 1u);
    return (unsigned short)(r >> 16);
}
__device__ __forceinline__ float b2f(unsigned short s) {
    return __builtin_bit_cast(float, ((unsigned)s) << 16);
}

__device__ __forceinline__ f32x4 MF(s16x8 a, s16x8 b, f32x4 c) {
    return __builtin_amdgcn_mfma_f32_16x16x32_bf16(
        __builtin_bit_cast(bf16x8, a), __builtin_bit_cast(bf16x8, b), c, 0, 0, 0);
}

// ---------------------------------------------------------------------------
// Gram partial, symmetric-packed. grid (BB, KS), block 256 (4 waves).
// 64 cols per iteration, double-buffered; each wave computes 9 of the 36
// unique 16x16 tiles (A/B fragments are the same row-fragments -> load all 8).
// ---------------------------------------------------------------------------
__global__ __launch_bounds__(256, 1)
void gram_kernel(const float* __restrict__ x, float* __restrict__ Gpart,
                 float* __restrict__ rspart)
{
    __shared__ short Xs[2][2][128 * SSTR];   // [buf][hi/lo][row*SSTR+col]
    const int b = blockIdx.x, ks = blockIdx.y;
    const int tid  = threadIdx.x;
    const int wave = tid >> 6, lane = tid & 63;
    const int q = lane >> 4, l15 = lane & 15;

    const float* __restrict__ Xb = x + (size_t)b * CC * NN + (size_t)ks * KCHUNK;
    const int lrow = tid >> 3;        // 0..31
    const int lc   = (tid & 7) * 8;   // 0,8,..,56

    f32x4 acc[9];
#pragma unroll
    for (int t = 0; t < 9; ++t) acc[t] = (f32x4){0.f, 0.f, 0.f, 0.f};
    float rs[4] = {0.f, 0.f, 0.f, 0.f};

    float4 ld[4][2];
#pragma unroll
    for (int p = 0; p < 4; ++p) {
        const float* row = Xb + (size_t)(lrow + 32 * p) * NN + lc;
        ld[p][0] = *(const float4*)(row);
        ld[p][1] = *(const float4*)(row + 4);
    }

#pragma unroll
    for (int p = 0; p < 4; ++p) {
        const int off = (lrow + 32 * p) * SSTR + lc;
#pragma unroll
        for (int h = 0; h < 2; ++h) {
            const float4 v = ld[p][h];
            rs[p] += v.x + v.y + v.z + v.w;
            float f[4] = {v.x, v.y, v.z, v.w};
            s16x4 hh, ll;
#pragma unroll
            for (int r = 0; r < 4; ++r) {
                unsigned short hb = f2b(f[r]);
                hh[r] = (short)hb;
                ll[r] = (short)f2b(f[r] - b2f(hb));
            }
            *(s16x4*)(&Xs[0][0][off + 4 * h]) = hh;
            *(s16x4*)(&Xs[0][1][off + 4 * h]) = ll;
        }
    }
    __syncthreads();

    for (int it = 0; it < 7; ++it) {
        const int cur = it & 1;
        if (it < 6) {
#pragma unroll
            for (int p = 0; p < 4; ++p) {
                const float* row = Xb + (size_t)(lrow + 32 * p) * NN + (it + 1) * 64 + lc;
                ld[p][0] = *(const float4*)(row);
                ld[p][1] = *(const float4*)(row + 4);
            }
        }
#pragma unroll
        for (int kk = 0; kk < 2; ++kk) {
            s16x8 fh[8], fl[8];
#pragma unroll
            for (int g = 0; g < 8; ++g) {
                const int ra = (g * 16 + l15) * SSTR + kk * 32 + q * 8;
                fh[g] = *(const s16x8*)(&Xs[cur][0][ra]);
                fl[g] = *(const s16x8*)(&Xs[cur][1][ra]);
            }
            // split-bf16 product: hh + h*lo + lo*h (ll dropped)
#define T3(i, j, t) { acc[t] = MF(fh[i], fh[j], acc[t]); \
                      acc[t] = MF(fh[i], fl[j], acc[t]); \
                      acc[t] = MF(fl[i], fh[j], acc[t]); }
            if (wave == 0)      { T3(0,0,0) T3(0,1,1) T3(0,2,2) T3(0,3,3) T3(0,4,4) T3(0,5,5) T3(0,6,6) T3(0,7,7) T3(1,1,8) }
            else if (wave == 1) { T3(1,2,0) T3(1,3,1) T3(1,4,2) T3(1,5,3) T3(1,6,4) T3(1,7,5) T3(2,2,6) T3(2,3,7) T3(2,4,8) }
            else if (wave == 2) { T3(2,5,0) T3(2,6,1) T3(2,7,2) T3(3,3,3) T3(3,4,4) T3(3,5,5) T3(3,6,6) T3(3,7,7) T3(4,4,8) }
            else                { T3(4,5,0) T3(4,6,1) T3(4,7,2) T3(5,5,3) T3(5,6,4) T3(5,7,5) T3(6,6,6) T3(6,7,7) T3(7,7,8) }
#undef T3
        }
        if (it < 6) {
#pragma unroll
            for (int p = 0; p < 4; ++p) {
                const int off = (lrow + 32 * p) * SSTR + lc;
#pragma unroll
                for (int h = 0; h < 2; ++h) {
                    const float4 v = ld[p][h];
                    rs[p] += v.x + v.y + v.z + v.w;
                    float f[4] = {v.x, v.y, v.z, v.w};
                    s16x4 hh, ll;
#pragma unroll
                    for (int r = 0; r < 4; ++r) {
                        unsigned short hb = f2b(f[r]);
                        hh[r] = (short)hb;
                        ll[r] = (short)f2b(f[r] - b2f(hb));
                    }
                    *(s16x4*)(&Xs[cur ^ 1][0][off + 4 * h]) = hh;
                    *(s16x4*)(&Xs[cur ^ 1][1][off + 4 * h]) = ll;
                }
            }
            __syncthreads();
        }
    }

    // packed store: wave's 9 tiles at slots wave*9 .. wave*9+8
    float* __restrict__ Gb = Gpart + ((size_t)(ks * BB + b) * NTILE + wave * 9) * 256;
#pragma unroll
    for (int t = 0; t < 9; ++t)
#pragma unroll
        for (int r = 0; r < 4; ++r)
            Gb[t * 256 + (q * 4 + r) * 16 + l15] = acc[t][r];

#pragma unroll
    for (int p = 0; p < 4; ++p) {
        float v = rs[p];
        v += __shfl_xor(v, 1);
        v += __shfl_xor(v, 2);
        v += __shfl_xor(v, 4);
        if ((lane & 7) == 0)
            rspart[(size_t)(ks * BB + b) * CC + lrow + 32 * p] = v;
    }
}

// ---------------------------------------------------------------------------
// Fused reduce + NS: 1024 threads (16 waves, 4/SIMD). Prologue sums the 7
// packed K-partials in fp32, computes sigma, trace (in-block), and writes the
// XOR-swizzled planes with symmetric mirroring. Then the NS iterations:
// P1 (D = 0.5I - 0.5*Z@Y) on all 16 waves (32x32 tiles);
// P2 (Y += Y@D, waves 0-7) || P3 (Z += D@Z, waves 8-15), 16x128 strips.
// All NS matrices symmetric -> transposed packed LDS writes are valid.
// ---------------------------------------------------------------------------
__global__ __launch_bounds__(1024, 4)
void ns_kernel(const float* __restrict__ Gpart, const float* __restrict__ rspart,
               float* __restrict__ out)
{
    __shared__ short Yhi[MATS];
    __shared__ short Ylo[MATS];
    __shared__ short Dm [MATS];
    __shared__ short Zm [MATS];
    __shared__ float mu[CC];
    __shared__ float red[16];

    const int b = blockIdx.x;
    const int tid  = threadIdx.x;
    const int wave = tid >> 6, lane = tid & 63;
    const int q = lane >> 4, l15 = lane & 15;

    // ---- mu = rowsum/n ----
    if (tid < CC) {
        float s = 0.f;
#pragma unroll
        for (int ks = 0; ks < KS; ++ks)
            s += rspart[(size_t)(ks * BB + b) * CC + tid];
        mu[tid] = s * (1.0f / NN);
    }
    __syncthreads();

    // ---- sum packed partials -> sigma (fp32) + trace partial ----
    const int r16 = (tid >> 4) & 15;   // within-tile row
    const int c16 = tid & 15;          // within-tile col
    const int s0  = tid >> 8;          // slot low bits (uniform per wave)

    float sg[9];
    float trp = 0.f;
#pragma unroll
    for (int jj = 0; jj < 9; ++jj) {
        float g = 0.f;
#pragma unroll
        for (int ks = 0; ks < KS; ++ks)
            g += Gpart[(size_t)(ks * BB + b) * (NTILE * 256) + tid + 1024 * jj];
        const int sl = s0 + 4 * jj;
        const int ti = SLI[sl], tj = SLJ[sl];
        const float sig = g * (1.0f / NN) - mu[ti * 16 + r16] * mu[tj * 16 + c16];
        sg[jj] = sig;
        if (ti == tj && r16 == c16) trp += sig;
    }
#pragma unroll
    for (int d = 1; d < 64; d <<= 1) trp += __shfl_xor(trp, d);
    if (lane == 0) red[wave] = trp;
    __syncthreads();
    float tr = 0.f;
#pragma unroll
    for (int w = 0; w < 16; ++w) tr += red[w];
    const float invtr = 1.0f / tr;
    const float sscale = sqrtf(tr);

    // ---- planes: Y1 = A = sigma/tr (split), D1 = 0.5I-0.5A, Z1 = I+D1 ----
#pragma unroll
    for (int jj = 0; jj < 9; ++jj) {
        const int sl = s0 + 4 * jj;
        const int ti = SLI[sl], tj = SLJ[sl];
        const int row = ti * 16 + r16, col = tj * 16 + c16;
        const float a = sg[jj] * invtr;
        const unsigned short hh = f2b(a);
        const unsigned short ll = f2b(a - b2f(hh));
        const float dia = (row == col) ? 0.5f : 0.0f;
        const float d = dia - 0.5f * a;
        const unsigned short db = f2b(d);
        const unsigned short zb = f2b(((row == col) ? 1.0f : 0.0f) + d);
        const int o1 = NSW(row, col);
        Yhi[o1] = (short)hh; Ylo[o1] = (short)ll;
        Dm [o1] = (short)db; Zm [o1] = (short)zb;
        if (ti != tj) {      // mirror: all these matrices are symmetric
            const int o2 = NSW(col, row);
            Yhi[o2] = (short)hh; Ylo[o2] = (short)ll;
            Dm [o2] = (short)db; Zm [o2] = (short)zb;
        }
    }
    __syncthreads();

    const int half = wave >> 3;          // 0: Y-group (P2), 1: Z-group (P3)
    const int ri0  = (wave & 7) * 16;    // strip row base for P2/P3
    const int p1i  = (wave >> 2) * 32;   // P1 tile coords (4x4 grid of 32x32)
    const int p1j  = (wave & 3) * 32;

    f32x4 acc8[8];

    // ======== it1: P2 only (Y2 = Y1 + Y1@D1; Z1 already equals T1) ========
#pragma unroll
    for (int ct = 0; ct < 8; ++ct) acc8[ct] = (f32x4){0.f, 0.f, 0.f, 0.f};
    if (half == 0) {
#pragma unroll
        for (int k0 = 0; k0 < 128; k0 += 32) {
            const int ka = k0 + q * 8;
            s16x8 ah = *(const s16x8*)(&Yhi[NSW(ri0 + l15, ka)]);
            s16x8 al = *(const s16x8*)(&Ylo[NSW(ri0 + l15, ka)]);
            s16x8 bv[8];
#pragma unroll
            for (int ct = 0; ct < 8; ++ct)
                bv[ct] = *(const s16x8*)(&Dm[NSW(ct * 16 + l15, ka)]);
#pragma unroll
            for (int ct = 0; ct < 8; ++ct) {
                acc8[ct] = MF(ah, bv[ct], acc8[ct]);
                acc8[ct] = MF(al, bv[ct], acc8[ct]);
            }
        }
    }
    __syncthreads();
    if (half == 0) {
        const int m0 = ri0 + q * 4;
#pragma unroll
        for (int ct = 0; ct < 8; ++ct) {
            const int n = ct * 16 + l15;
            const int off = NSW(n, m0);
            s16x4 yh = *(s16x4*)(&Yhi[off]);
            s16x4 yl = *(s16x4*)(&Ylo[off]);
            s16x4 nh, nl;
#pragma unroll
            for (int r = 0; r < 4; ++r) {
                const float y = b2f((unsigned short)yh[r]) + b2f((unsigned short)yl[r]) + acc8[ct][r];
                unsigned short hh = f2b(y);
                nh[r] = (short)hh;
                nl[r] = (short)f2b(y - b2f(hh));
            }
            *(s16x4*)(&Yhi[off]) = nh;
            *(s16x4*)(&Ylo[off]) = nl;
        }
    }
    __syncthreads();

    // ======== it2..4: full update ========
#pragma unroll 1
    for (int it = 2; it <= 4; ++it) {
        // P1 (all 16 waves): D = 0.5I - 0.5 * Z@Y (Y ~ Yhi)
        f32x4 acc4[2][2];
#pragma unroll
        for (int rt = 0; rt < 2; ++rt)
#pragma unroll
            for (int ct = 0; ct < 2; ++ct) acc4[rt][ct] = (f32x4){0.f, 0.f, 0.f, 0.f};
#pragma unroll
        for (int k0 = 0; k0 < 128; k0 += 32) {
            const int ka = k0 + q * 8;
            s16x8 av[2], bv[2];
#pragma unroll
            for (int t = 0; t < 2; ++t) {
                av[t] = *(const s16x8*)(&Zm [NSW(p1i + t * 16 + l15, ka)]);
                bv[t] = *(const s16x8*)(&Yhi[NSW(p1j + t * 16 + l15, ka)]);
            }
#pragma unroll
            for (int rt = 0; rt < 2; ++rt)
#pragma unroll
                for (int ct = 0; ct < 2; ++ct)
                    acc4[rt][ct] = MF(av[rt], bv[ct], acc4[rt][ct]);
        }
#pragma unroll
        for (int rt = 0; rt < 2; ++rt)
#pragma unroll
            for (int ct = 0; ct < 2; ++ct) {
                const int m0 = p1i + rt * 16 + q * 4;
                const int n  = p1j + ct * 16 + l15;
                s16x4 dv;
#pragma unroll
                for (int r = 0; r < 4; ++r) {
                    const float dia = (m0 + r == n) ? 0.5f : 0.0f;
                    dv[r] = (short)f2b(dia - 0.5f * acc4[rt][ct][r]);
                }
                *(s16x4*)(&Dm[NSW(n, m0)]) = dv;
            }
        __syncthreads();

        // P2 (waves 0-7) || P3 (waves 8-15)
#pragma unroll
        for (int ct = 0; ct < 8; ++ct) acc8[ct] = (f32x4){0.f, 0.f, 0.f, 0.f};
        if (half == 0) {
#pragma unroll
            for (int k0 = 0; k0 < 128; k0 += 32) {
                const int ka = k0 + q * 8;
                s16x8 ah = *(const s16x8*)(&Yhi[NSW(ri0 + l15, ka)]);
                s16x8 al = *(const s16x8*)(&Ylo[NSW(ri0 + l15, ka)]);
                s16x8 bv[8];
#pragma unroll
                for (int ct = 0; ct < 8; ++ct)
                    bv[ct] = *(const s16x8*)(&Dm[NSW(ct * 16 + l15, ka)]);
#pragma unroll
                for (int ct = 0; ct < 8; ++ct) {
                    acc8[ct] = MF(ah, bv[ct], acc8[ct]);
                    acc8[ct] = MF(al, bv[ct], acc8[ct]);
                }
            }
        } else {
#pragma unroll
            for (int k0 = 0; k0 < 128; k0 += 32) {
                const int ka = k0 + q * 8;
                s16x8 av = *(const s16x8*)(&Dm[NSW(ri0 + l15, ka)]);
                s16x8 bv[8];
#pragma unroll
                for (int ct = 0; ct < 8; ++ct)
                    bv[ct] = *(const s16x8*)(&Zm[NSW(ct * 16 + l15, ka)]);
#pragma unroll
                for (int ct = 0; ct < 8; ++ct)
                    acc8[ct] = MF(av, bv[ct], acc8[ct]);
            }
        }
        __syncthreads();   // all plane reads complete before rewrites

        const int m0 = ri0 + q * 4;
        if (half == 0) {
#pragma unroll
            for (int ct = 0; ct < 8; ++ct) {
                const int n = ct * 16 + l15;
                const int off = NSW(n, m0);
                s16x4 yh = *(s16x4*)(&Yhi[off]);
                s16x4 yl = *(s16x4*)(&Ylo[off]);
                s16x4 nh, nl;
#pragma unroll
                for (int r = 0; r < 4; ++r) {
                    const float y = b2f((unsigned short)yh[r]) + b2f((unsigned short)yl[r]) + acc8[ct][r];
                    unsigned short hh = f2b(y);
                    nh[r] = (short)hh;
                    nl[r] = (short)f2b(y - b2f(hh));
                }
                *(s16x4*)(&Yhi[off]) = nh;
                *(s16x4*)(&Ylo[off]) = nl;
            }
        } else {
#pragma unroll
            for (int ct = 0; ct < 8; ++ct) {
                const int n = ct * 16 + l15;
                const int off = NSW(n, m0);
                s16x4 zv = *(s16x4*)(&Zm[off]);
                s16x4 zn;
#pragma unroll
                for (int r = 0; r < 4; ++r)
                    zn[r] = (short)f2b(b2f((unsigned short)zv[r]) + acc8[ct][r]);
                *(s16x4*)(&Zm[off]) = zn;
            }
        }
        __syncthreads();
    }

    // ======== it5: P1, then P2 -> output ========
    {
        f32x4 acc4[2][2];
#pragma unroll
        for (int rt = 0; rt < 2; ++rt)
#pragma unroll
            for (int ct = 0; ct < 2; ++ct) acc4[rt][ct] = (f32x4){0.f, 0.f, 0.f, 0.f};
#pragma unroll
        for (int k0 = 0; k0 < 128; k0 += 32) {
            const int ka = k0 + q * 8;
            s16x8 av[2], bv[2];
#pragma unroll
            for (int t = 0; t < 2; ++t) {
                av[t] = *(const s16x8*)(&Zm [NSW(p1i + t * 16 + l15, ka)]);
                bv[t] = *(const s16x8*)(&Yhi[NSW(p1j + t * 16 + l15, ka)]);
            }
#pragma unroll
            for (int rt = 0; rt < 2; ++rt)
#pragma unroll
                for (int ct = 0; ct < 2; ++ct)
                    acc4[rt][ct] = MF(av[rt], bv[ct], acc4[rt][ct]);
        }
#pragma unroll
        for (int rt = 0; rt < 2; ++rt)
#pragma unroll
            for (int ct = 0; ct < 2; ++ct) {
                const int m0 = p1i + rt * 16 + q * 4;
                const int n  = p1j + ct * 16 + l15;
                s16x4 dv;
#pragma unroll
                for (int r = 0; r < 4; ++r) {
                    const float dia = (m0 + r == n) ? 0.5f : 0.0f;
                    dv[r] = (short)f2b(dia - 0.5f * acc4[rt][ct][r]);
                }
                *(s16x4*)(&Dm[NSW(n, m0)]) = dv;
            }
        __syncthreads();

        if (half == 0) {
#pragma unroll
            for (int ct = 0; ct < 8; ++ct) acc8[ct] = (f32x4){0.f, 0.f, 0.f, 0.f};
#pragma unroll
            for (int k0 = 0; k0 < 128; k0 += 32) {
                const int ka = k0 + q * 8;
                s16x8 ah = *(const s16x8*)(&Yhi[NSW(ri0 + l15, ka)]);
                s16x8 al = *(const s16x8*)(&Ylo[NSW(ri0 + l15, ka)]);
                s16x8 bv[8];
#pragma unroll
                for (int ct = 0; ct < 8; ++ct)
                    bv[ct] = *(const s16x8*)(&Dm[NSW(ct * 16 + l15, ka)]);
#pragma unroll
                for (int ct = 0; ct < 8; ++ct) {
                    acc8[ct] = MF(ah, bv[ct], acc8[ct]);
                    acc8[ct] = MF(al, bv[ct], acc8[ct]);
                }
            }
            // out = triu(Y5 + Y5@D5) * sqrt(tr); Yhi/Ylo stable (no writers)
            float* __restrict__ ob = out + (size_t)b * OUTLEN;
            const int m0 = ri0 + q * 4;
#pragma unroll
            for (int ct = 0; ct < 8; ++ct) {
                const int n = ct * 16 + l15;
                const int off = NSW(n, m0);
                s16x4 yh = *(s16x4*)(&Yhi[off]);
                s16x4 yl = *(s16x4*)(&Ylo[off]);
#pragma unroll
                for (int r = 0; r < 4; ++r) {
                    const int m = m0 + r;
                    if (m <= n) {
                        const float y = b2f((unsigned short)yh[r]) + b2f((unsigned short)yl[r]) + acc8[ct][r];
                        ob[m * CC - ((m * (m - 1)) >> 1) + (n - m)] = y * sscale;
                    }
                }
            }
        }
    }
}

extern "C" void kernel_launch(void* const* d_in, const int* in_sizes, int n_in,
                              void* d_out, int out_size, void* d_ws, size_t ws_size,
                              hipStream_t stream)
{
    (void)in_sizes; (void)n_in; (void)out_size; (void)ws_size;
    const float* x = (const float*)d_in[0];
    float* out = (float*)d_out;
    float* ws  = (float*)d_ws;

    float* rspart = ws;                                   // KS*BB*CC floats
    float* Gpart  = rspart + (size_t)KS * BB * CC;        // KS*BB*NTILE*256 floats

    gram_kernel<<<dim3(BB, KS), 256, 0, stream>>>(x, Gpart, rspart);
    ns_kernel<<<dim3(BB), 1024, 0, stream>>>(Gpart, rspart, out);
}